// Round 15
// baseline (301.998 us; speedup 1.0000x reference)
//
#include <hip/hip_runtime.h>
#include <cstdint>

// Problem constants: B=2, S=2048, D=2048, H=16, DH=128
typedef unsigned short u16;
typedef __attribute__((ext_vector_type(8))) short short8v;       // 8 x bf16 (MFMA A/B frag)
typedef __attribute__((ext_vector_type(8))) unsigned short u16x8;
typedef __attribute__((ext_vector_type(4))) float floatx4;       // MFMA C/D frag

typedef unsigned int __attribute__((address_space(1))) as1_u32;
typedef unsigned int __attribute__((address_space(3))) as3_u32;

__device__ __forceinline__ u16 f2bf(float f) {
  union { float f; unsigned u; } v; v.f = f;
  unsigned r = v.u + 0x7FFFu + ((v.u >> 16) & 1u);   // RNE
  return (u16)(r >> 16);
}

__device__ __forceinline__ unsigned cvt_pk_bf16(float lo, float hi) {
  unsigned r;
  asm("v_cvt_pk_bf16_f32 %0, %1, %2" : "=v"(r) : "v"(lo), "v"(hi));
  return r;
}

__device__ __forceinline__ void gload16(void* lds, const void* g) {
  __builtin_amdgcn_global_load_lds((as1_u32*)(uintptr_t)g, (as3_u32*)(uintptr_t)lds, 16, 0, 0);
}

// ---------------- fused fp32 -> bf16 conversion (3 segments, 1 launch) ----------------
__global__ __launch_bounds__(256)
void f2bf3_kernel(const float* __restrict__ in0, u16* __restrict__ out0, int n0,
                  const float* __restrict__ in1, u16* __restrict__ out1, int n1,
                  const float* __restrict__ in2, u16* __restrict__ out2, int n2) {
  int i = blockIdx.x * 256 + threadIdx.x;
  const int stride = gridDim.x * 256;
  const int total = n0 + n1 + n2;
  for (; i < total; i += stride) {
    const float* src; u16* dst; int k;
    if (i < n0)            { src = in0; dst = out0; k = i; }
    else if (i < n0 + n1)  { src = in1; dst = out1; k = i - n0; }
    else                   { src = in2; dst = out2; k = i - n0 - n1; }
    float4 v = ((const float4*)src)[k];
    ushort4 o;
    o.x = f2bf(v.x); o.y = f2bf(v.y); o.z = f2bf(v.z); o.w = f2bf(v.w);
    ((ushort4*)dst)[k] = o;
  }
}

// ---------- QKV GEMM: 128x128 BK=32, 256 thr / 4 waves, 3-slot, 3 blocks/CU ----------
// gemm_s structure (proven for out-proj) applied to QKV: 48KB LDS -> 3 blocks/CU,
// three independent barrier domains interleave LDS bursts with MFMA bursts.
// Grid 32x48 = 1536 blocks (6/CU, 3-deep) — perfect balance. Same super-row
// swizzle (2 rows per 128B, XOR 16B-slot by pr&7; conflict-free, both-sides).
// Ledger (4 gload16/stage): prologue t0,t1 -> vmcnt(4); per tile {8 ds_read;
// stage t+2; 16 MFMA; vmcnt(4); barrier} — never 0 mid-loop.
// SPLIT_V: bcol>=4096 blocks write their C-tile TRANSPOSED into VT[b*16+h][dh][s]
// (hh uniform per block since head width 128 == tile width).
__global__ __launch_bounds__(256, 4)
void gemm_qkv(const u16* __restrict__ A, const u16* __restrict__ B,
              const float* __restrict__ bias, u16* __restrict__ C,
              u16* __restrict__ VT, int M, int N, int K) {
  __shared__ u16 Al[3][4096];   // 24KB
  __shared__ u16 Bl[3][4096];   // 24KB
  const int tid = threadIdx.x;
  const int wid = tid >> 6, lane = tid & 63;
  const int wr = wid >> 1, wc = wid & 1;
  const int li = lane & 15, lg = lane >> 4;
  const int nwg = gridDim.x;
  const int bid = blockIdx.x;
  const int swz = (bid & 7) * (nwg >> 3) + (bid >> 3);   // XCD-bijective (nwg%8==0)
  const int mcnt = M >> 7;
  const int bm = swz % mcnt, bn = swz / mcnt;            // bm-fastest: B-panels L2-hot
  const int brow = bm * 128, bcol = bn * 128;
  const int NT = K >> 5;                                 // BK=32

  const int P = tid * 16;                                 // 0..4095
  const int pr = P >> 7;
  const int innerLog = (P & 127) ^ ((pr & 7) << 4);
  const int srow = (pr << 1) + (innerLog >> 6);           // 0..63
  const int skb = innerLog & 63;
  const u16* aS = A + (size_t)(brow + srow) * K + (skb >> 1);
  const u16* bS = B + (size_t)(bcol + srow) * K + (skb >> 1);

#define STG(slot, kt_)                                                          \
  {                                                                             \
    const u16* a_ = aS + (kt_) * 32;                                            \
    const u16* b_ = bS + (kt_) * 32;                                            \
    gload16((char*)&Al[slot][0] + P, a_);                                       \
    gload16((char*)&Al[slot][0] + 4096 + P, a_ + (size_t)64 * K);               \
    gload16((char*)&Bl[slot][0] + P, b_);                                       \
    gload16((char*)&Bl[slot][0] + 4096 + P, b_ + (size_t)64 * K);               \
  }

  floatx4 acc[4][4];
#pragma unroll
  for (int m = 0; m < 4; ++m)
#pragma unroll
    for (int n = 0; n < 4; ++n) acc[m][n] = floatx4{0.f, 0.f, 0.f, 0.f};

  const int fxor = ((li >> 1) & 7) << 4;
  const int finner = (((li & 1) << 6) + (lg << 4)) ^ fxor;
  const int aoff = (wr * 32 + (li >> 1)) * 128 + finner;
  const int boff = (wc * 32 + (li >> 1)) * 128 + finner;

  STG(0, 0);
  STG(1, 1);
  asm volatile("s_waitcnt vmcnt(4)" ::: "memory");
  __builtin_amdgcn_s_barrier();

  int sl = 0;
  for (int t = 0; t < NT; ++t) {
    const char* Ab = (const char*)&Al[sl][0];
    const char* Bb = (const char*)&Bl[sl][0];
    short8v af[4], bf[4];
#pragma unroll
    for (int m = 0; m < 4; ++m) af[m] = *(const short8v*)(Ab + aoff + m * 1024);
#pragma unroll
    for (int n = 0; n < 4; ++n) bf[n] = *(const short8v*)(Bb + boff + n * 1024);

    int s2 = sl + 2; if (s2 >= 3) s2 -= 3;
    if (t + 2 < NT) STG(s2, t + 2);

    __builtin_amdgcn_s_setprio(1);
#pragma unroll
    for (int m = 0; m < 4; ++m)
#pragma unroll
      for (int n = 0; n < 4; ++n)
        acc[m][n] = __builtin_amdgcn_mfma_f32_16x16x32_bf16(af[m], bf[n], acc[m][n], 0, 0, 0);
    __builtin_amdgcn_s_setprio(0);

    if (t + 2 < NT)      asm volatile("s_waitcnt vmcnt(4)" ::: "memory");
    else if (t + 1 < NT) asm volatile("s_waitcnt vmcnt(0)" ::: "memory");
    __builtin_amdgcn_s_barrier();
    sl = (sl + 1 == 3) ? 0 : sl + 1;
  }
#undef STG

  const int crow0 = brow + wr * 64 + lg * 4;
  const int ccol0 = bcol + wc * 64 + li;
  if (bcol >= 4096) {
    // V region -> write transposed into VT[(b*16+h)*128+dh][s]
    const int bb = crow0 >> 11;                 // uniform per block
    const int s0b = (crow0 & 2047);             // + m*16 (+j within ushort4)
    const int hh = (bcol - 4096) >> 7;          // uniform per block (tile width == head width)
#pragma unroll
    for (int n = 0; n < 4; ++n) {
      const int dh = wc * 64 + n * 16 + li;
      const float bv = bias[ccol0 + n * 16];
      u16* drow = VT + ((size_t)(bb * 16 + hh) * 128 + dh) * 2048;
#pragma unroll
      for (int m = 0; m < 4; ++m) {
        ushort4 o;
        o.x = f2bf(acc[m][n][0] + bv);
        o.y = f2bf(acc[m][n][1] + bv);
        o.z = f2bf(acc[m][n][2] + bv);
        o.w = f2bf(acc[m][n][3] + bv);
        *(ushort4*)(drow + s0b + m * 16) = o;
      }
    }
  } else {
#pragma unroll
    for (int n = 0; n < 4; ++n) {
      const float bv = bias[ccol0 + n * 16];
#pragma unroll
      for (int m = 0; m < 4; ++m) {
#pragma unroll
        for (int j = 0; j < 4; ++j) {
          const float v = acc[m][n][j] + bv;
          C[(size_t)(crow0 + m * 16 + j) * N + (ccol0 + n * 16)] = f2bf(v);
        }
      }
    }
  }
}

// ---------------- 128x128 BK=32 GEMM, 256 thr, 3-slot, 3 blocks/CU (out-proj) ------
template <int OUT_BF16>
__global__ __launch_bounds__(256, 4)
void gemm_s(const u16* __restrict__ A, const u16* __restrict__ B,
            const float* __restrict__ bias, void* __restrict__ C,
            int M, int N, int K) {
  __shared__ u16 Al[3][4096];   // 24KB
  __shared__ u16 Bl[3][4096];   // 24KB
  const int tid = threadIdx.x;
  const int wid = tid >> 6, lane = tid & 63;
  const int wr = wid >> 1, wc = wid & 1;
  const int li = lane & 15, lg = lane >> 4;
  const int nwg = gridDim.x;
  const int bid = blockIdx.x;
  const int swz = (bid & 7) * (nwg >> 3) + (bid >> 3);   // XCD-bijective
  const int mcnt = M >> 7;
  const int bm = swz % mcnt, bn = swz / mcnt;
  const int brow = bm * 128, bcol = bn * 128;
  const int NT = K >> 5;

  const int P = tid * 16;                                 // 0..4095
  const int pr = P >> 7;
  const int innerLog = (P & 127) ^ ((pr & 7) << 4);
  const int srow = (pr << 1) + (innerLog >> 6);           // 0..63
  const int skb = innerLog & 63;
  const u16* aS = A + (size_t)(brow + srow) * K + (skb >> 1);
  const u16* bS = B + (size_t)(bcol + srow) * K + (skb >> 1);

#define STG(slot, kt_)                                                          \
  {                                                                             \
    const u16* a_ = aS + (kt_) * 32;                                            \
    const u16* b_ = bS + (kt_) * 32;                                            \
    gload16((char*)&Al[slot][0] + P, a_);                                       \
    gload16((char*)&Al[slot][0] + 4096 + P, a_ + (size_t)64 * K);               \
    gload16((char*)&Bl[slot][0] + P, b_);                                       \
    gload16((char*)&Bl[slot][0] + 4096 + P, b_ + (size_t)64 * K);               \
  }

  floatx4 acc[4][4];
#pragma unroll
  for (int m = 0; m < 4; ++m)
#pragma unroll
    for (int n = 0; n < 4; ++n) acc[m][n] = floatx4{0.f, 0.f, 0.f, 0.f};

  const int fxor = ((li >> 1) & 7) << 4;
  const int finner = (((li & 1) << 6) + (lg << 4)) ^ fxor;
  const int aoff = (wr * 32 + (li >> 1)) * 128 + finner;
  const int boff = (wc * 32 + (li >> 1)) * 128 + finner;

  STG(0, 0);
  STG(1, 1);
  asm volatile("s_waitcnt vmcnt(4)" ::: "memory");
  __builtin_amdgcn_s_barrier();

  int sl = 0;
  for (int t = 0; t < NT; ++t) {
    const char* Ab = (const char*)&Al[sl][0];
    const char* Bb = (const char*)&Bl[sl][0];
    short8v af[4], bf[4];
#pragma unroll
    for (int m = 0; m < 4; ++m) af[m] = *(const short8v*)(Ab + aoff + m * 1024);
#pragma unroll
    for (int n = 0; n < 4; ++n) bf[n] = *(const short8v*)(Bb + boff + n * 1024);

    int s2 = sl + 2; if (s2 >= 3) s2 -= 3;
    if (t + 2 < NT) STG(s2, t + 2);

    __builtin_amdgcn_s_setprio(1);
#pragma unroll
    for (int m = 0; m < 4; ++m)
#pragma unroll
      for (int n = 0; n < 4; ++n)
        acc[m][n] = __builtin_amdgcn_mfma_f32_16x16x32_bf16(af[m], bf[n], acc[m][n], 0, 0, 0);
    __builtin_amdgcn_s_setprio(0);

    if (t + 2 < NT)      asm volatile("s_waitcnt vmcnt(4)" ::: "memory");
    else if (t + 1 < NT) asm volatile("s_waitcnt vmcnt(0)" ::: "memory");
    __builtin_amdgcn_s_barrier();
    sl = (sl + 1 == 3) ? 0 : sl + 1;
  }
#undef STG

  const int crow0 = brow + wr * 64 + lg * 4;
  const int ccol0 = bcol + wc * 64 + li;
#pragma unroll
  for (int n = 0; n < 4; ++n) {
    const float bv = bias[ccol0 + n * 16];
#pragma unroll
    for (int m = 0; m < 4; ++m) {
#pragma unroll
      for (int j = 0; j < 4; ++j) {
        const float v = acc[m][n][j] + bv;
        const size_t idx = (size_t)(crow0 + m * 16 + j) * N + (ccol0 + n * 16);
        if (OUT_BF16) ((u16*)C)[idx] = f2bf(v);
        else          ((float*)C)[idx] = v;
      }
    }
  }
}

// ---------------- fused causal flash attention (round-8 structure + T5 setprio) ----
__global__ __launch_bounds__(256, 2)
void attn_fused(const u16* __restrict__ qkv, const u16* __restrict__ vt,
                const int* __restrict__ kpm, u16* __restrict__ attn_out) {
  constexpr int S = 2048, DQ = 6144;
  __shared__ u16 Kl[2][64 * 128];   // 32KB, double-buffered; reused as O-staging
  __shared__ u16 Vl[128 * 64];      // 16KB
  __shared__ float mskf[2048];      // 8KB additive pad penalties
  __shared__ int s_any;
  const int bx = blockIdx.x, by = blockIdx.y;
  const int qt = ((by >> 4) & 1) ? bx : (15 - bx);   // co-resident qt balance
  const int bh = by;
  const int b = bh >> 4, h = bh & 15;
  const int tid = threadIdx.x, wave = tid >> 6, lane = tid & 63;
  const int lg = lane >> 4, li = lane & 15;
  const int qrow0 = qt * 128 + wave * 32;

  const u16* Qb = qkv + (size_t)b * S * DQ + h * 128;
  const u16* Kb = Qb + 2048;
  const u16* Vtb = vt + (size_t)bh * 128 * 2048;
  const int* mrow = kpm + b * S;

  if (tid == 0) s_any = 0;
  __syncthreads();
  {
    int a = 0;
    for (int j = tid; j < 2048; j += 256) {
      const int mv = mrow[j];
      mskf[j] = mv ? 0.f : -1.0e9f;
      if (mv && j <= qt * 128) a = 1;
    }
    if (a) s_any = 1;
  }
  __syncthreads();
  const int anyv = s_any;
  const int nt = anyv ? (2 * qt + 2) : 32;
  const int causalFromW = anyv ? (qrow0 >> 6) : 0;

  short8v qb[2][4];
#pragma unroll
  for (int m = 0; m < 2; ++m) {
    const u16* qp = Qb + (size_t)(qrow0 + m * 16 + li) * DQ + lg * 8;
#pragma unroll
    for (int kk = 0; kk < 4; ++kk) qb[m][kk] = *(const short8v*)(qp + kk * 32);
  }
  asm volatile("s_waitcnt vmcnt(0)" ::: "memory");  // clean VMEM ledger

  float mM[2], lSum[2];
  floatx4 oa[2][8];
#pragma unroll
  for (int m = 0; m < 2; ++m) {
    mM[m] = -3.0e38f; lSum[m] = 0.f;
#pragma unroll
    for (int n = 0; n < 8; ++n) oa[m][n] = floatx4{0.f, 0.f, 0.f, 0.f};
  }

  const u16* kSrc[4]; const u16* vSrc[4];
#pragma unroll
  for (int i = 0; i < 4; ++i) {
    const int L = i * 4096 + tid * 16;
    const int r = L >> 8;
    const int c = ((L & 255) ^ ((r & 7) << 4)) >> 1;
    kSrc[i] = Kb + (size_t)r * DQ + c;
    const int d = L >> 7;
    const int sv = ((L & 127) ^ ((d & 7) << 4)) >> 1;
    vSrc[i] = Vtb + (size_t)d * 2048 + sv;
  }

#define STAGE_K(buf, kt_)                                                      \
  {                                                                            \
    const int kv0_ = (kt_) * 64;                                               \
    _Pragma("unroll")                                                          \
    for (int i = 0; i < 4; ++i)                                                \
      gload16((char*)Kl + (buf) * 16384 + i * 4096 + tid * 16,                 \
              kSrc[i] + (size_t)kv0_ * DQ);                                    \
  }
#define STAGE_V(kt_)                                                           \
  {                                                                            \
    const int kv0_ = (kt_) * 64;                                               \
    _Pragma("unroll")                                                          \
    for (int i = 0; i < 4; ++i)                                                \
      gload16((char*)Vl + i * 4096 + tid * 16, vSrc[i] + kv0_);                \
  }

  const float scale = 0.08838834764831845f;  // 1/sqrt(128)

  STAGE_K(0, 0);
  STAGE_V(0);

  for (int kt = 0; kt < nt; ++kt) {
    const int cur = kt & 1;
    const int kv0 = kt * 64;
    if (kt + 1 < nt) {
      STAGE_K(cur ^ 1, kt + 1);
      asm volatile("s_waitcnt vmcnt(8)" ::: "memory");
    } else {
      asm volatile("s_waitcnt vmcnt(4)" ::: "memory");
    }
    __builtin_amdgcn_s_barrier();

    const char* Kcur = (const char*)Kl + cur * 16384;

    floatx4 sc[2][4];
#pragma unroll
    for (int n = 0; n < 4; ++n) { sc[0][n] = floatx4{0,0,0,0}; sc[1][n] = floatx4{0,0,0,0}; }
    __builtin_amdgcn_s_setprio(1);
#pragma unroll
    for (int n = 0; n < 4; ++n) {
      const int r = n * 16 + li;
#pragma unroll
      for (int kk = 0; kk < 4; ++kk) {
        const int byteo = (r * 256 + kk * 64 + lg * 16) ^ ((r & 7) << 4);
        const short8v kf = *(const short8v*)(Kcur + byteo);
        sc[0][n] = __builtin_amdgcn_mfma_f32_16x16x32_bf16(kf, qb[0][kk], sc[0][n], 0, 0, 0);
        sc[1][n] = __builtin_amdgcn_mfma_f32_16x16x32_bf16(kf, qb[1][kk], sc[1][n], 0, 0, 0);
      }
    }
    __builtin_amdgcn_s_setprio(0);

    floatx4 pbv[4];
#pragma unroll
    for (int n = 0; n < 4; ++n)
      pbv[n] = *(const floatx4*)&mskf[kv0 + n * 16 + lg * 4];
    const bool cz = (kt >= causalFromW);

    short8v pf[2][2];
#pragma unroll
    for (int m = 0; m < 2; ++m) {
      const int q_l = qrow0 + m * 16 + li;
      float tmax = -3.0e38f;
#pragma unroll
      for (int n = 0; n < 4; ++n)
#pragma unroll
        for (int j = 0; j < 4; ++j) {
          float s = sc[m][n][j] * scale + pbv[n][j];
          if (cz && (kv0 + n * 16 + lg * 4 + j > q_l)) s -= 1.0e9f;
          sc[m][n][j] = s;
          tmax = fmaxf(tmax, s);
        }
      tmax = fmaxf(tmax, __shfl_xor(tmax, 16));
      tmax = fmaxf(tmax, __shfl_xor(tmax, 32));
      const float mnew = fmaxf(mM[m], tmax);
      const float f = __expf(mM[m] - mnew);
      mM[m] = mnew;
      float rs = 0.f;
#pragma unroll
      for (int n = 0; n < 4; ++n)
#pragma unroll
        for (int j = 0; j < 4; ++j) {
          const float e = __expf(sc[m][n][j] - mnew);
          sc[m][n][j] = e; rs += e;
        }
      rs += __shfl_xor(rs, 16);
      rs += __shfl_xor(rs, 32);
      lSum[m] = lSum[m] * f + rs;
#pragma unroll
      for (int n2 = 0; n2 < 8; ++n2) oa[m][n2] *= f;

      unsigned w32[4][2];
#pragma unroll
      for (int n = 0; n < 4; ++n) {
        w32[n][0] = cvt_pk_bf16(sc[m][n][0], sc[m][n][1]);
        w32[n][1] = cvt_pk_bf16(sc[m][n][2], sc[m][n][3]);
      }
      union PF { short8v s; unsigned w[4]; } pfu[2];
#pragma unroll
      for (int kk2 = 0; kk2 < 2; ++kk2) {
#pragma unroll
        for (int hh = 0; hh < 2; ++hh) {
          unsigned u = w32[2 * kk2][hh], v = w32[2 * kk2 + 1][hh];
          asm volatile("v_permlane32_swap_b32 %0, %1" : "+v"(u), "+v"(v));
          asm volatile("v_permlane16_swap_b32 %0, %1" : "+v"(u), "+v"(v));
          pfu[kk2].w[hh] = u;
          pfu[kk2].w[2 + hh] = v;
        }
      }
      pf[m][0] = pfu[0].s;
      pf[m][1] = pfu[1].s;
    }

    if (kt + 1 < nt) asm volatile("s_waitcnt vmcnt(4)" ::: "memory");
    else             asm volatile("s_waitcnt vmcnt(0)" ::: "memory");
    __builtin_amdgcn_s_barrier();

    __builtin_amdgcn_s_setprio(1);
#pragma unroll
    for (int kk2 = 0; kk2 < 2; ++kk2) {
#pragma unroll
      for (int n2 = 0; n2 < 8; ++n2) {
        const int d = n2 * 16 + li;
        const int vbyte = (d * 128 + kk2 * 64 + lg * 16) ^ ((d & 7) << 4);
        const short8v vf = *(const short8v*)((const char*)Vl + vbyte);
        oa[0][n2] = __builtin_amdgcn_mfma_f32_16x16x32_bf16(vf, pf[0][kk2], oa[0][n2], 0, 0, 0);
        oa[1][n2] = __builtin_amdgcn_mfma_f32_16x16x32_bf16(vf, pf[1][kk2], oa[1][n2], 0, 0, 0);
      }
    }
    __builtin_amdgcn_s_setprio(0);
    __builtin_amdgcn_s_barrier();
    if (kt + 1 < nt) STAGE_V(kt + 1);
  }

  {
    char* Ol = (char*)Kl + wave * 8192;
#pragma unroll
    for (int m = 0; m < 2; ++m) {
      const float inv = 1.0f / lSum[m];
      const int q_ = m * 16 + li;
#pragma unroll
      for (int n2 = 0; n2 < 8; ++n2) {
        unsigned lo = cvt_pk_bf16(oa[m][n2][0] * inv, oa[m][n2][1] * inv);
        unsigned hi = cvt_pk_bf16(oa[m][n2][2] * inv, oa[m][n2][3] * inv);
        const int byteo = (q_ * 256 + n2 * 32 + lg * 8) ^ ((q_ & 7) << 4);
        uint2 pr2; pr2.x = lo; pr2.y = hi;
        *(uint2*)(Ol + byteo) = pr2;
      }
    }
    asm volatile("s_waitcnt lgkmcnt(0)" ::: "memory");
#pragma unroll
    for (int rr = 0; rr < 4; ++rr) {
      const int r = rr * 8 + (lane >> 3);
      const size_t grow = (size_t)(b * 2048 + qt * 128 + wave * 32 + r) * 2048 + h * 128;
#pragma unroll
      for (int s2 = 0; s2 < 2; ++s2) {
        const int byteo = (r * 256 + (lane & 7) * 32 + s2 * 16) ^ ((r & 7) << 4);
        const u16x8 val = *(const u16x8*)(Ol + byteo);
        *(u16x8*)&attn_out[grow + (lane & 7) * 16 + s2 * 8] = val;
      }
    }
  }
#undef STAGE_K
#undef STAGE_V
}

// ---------------- launch ----------------
extern "C" void kernel_launch(void* const* d_in, const int* in_sizes, int n_in,
                              void* d_out, int out_size, void* d_ws, size_t ws_size,
                              hipStream_t stream) {
  const float* x    = (const float*)d_in[0];   // [2,2048,2048]
  const int*   kpm  = (const int*)d_in[1];     // [2,2048]
  const float* wqkv = (const float*)d_in[2];   // [6144,2048]
  const float* bqkv = (const float*)d_in[3];   // [6144]
  const float* wout = (const float*)d_in[4];   // [2048,2048]
  const float* bout = (const float*)d_in[5];   // [2048]
  float* out = (float*)d_out;

  char* ws = (char*)d_ws;
  u16* xbf   = (u16*)(ws);                    // 16 MiB: x bf16 [4096,2048]
  u16* wqbf  = (u16*)(ws + (16u << 20));      // 24 MiB: Wqkv bf16 [6144,2048]
  u16* wobf  = (u16*)(ws + (40u << 20));      //  8 MiB: out_w bf16 [2048,2048]
  u16* qkvb  = (u16*)(ws + (48u << 20));      // 48 MiB: qkv bf16 [4096,6144] (V third unused)
  u16* vtb   = (u16*)(ws + (96u << 20));      // 16 MiB: V^T bf16 [32,128,2048]
  u16* attnb = (u16*)(ws + (112u << 20));     // 16 MiB: attn bf16 [4096,2048]

  f2bf3_kernel<<<2048, 256, 0, stream>>>(x,    xbf,  4096 * 2048 / 4,
                                         wqkv, wqbf, 6144 * 2048 / 4,
                                         wout, wobf, 2048 * 2048 / 4);

  // QKV as 128x128 tiles: grid 32*48 = 1536 blocks (3 blocks/CU, 6 per CU, 3-deep)
  gemm_qkv<<<1536, 256, 0, stream>>>(xbf, wqbf, bqkv, qkvb, vtb, 4096, 6144, 2048);
  attn_fused<<<dim3(16, 32), 256, 0, stream>>>(qkvb, vtb, kpm, attnb);
  gemm_s<0><<<512, 256, 0, stream>>>(attnb, wobf, bout, out, 4096, 2048, 2048);
}

// Round 16
// 279.901 us; speedup vs baseline: 1.0789x; 1.0789x over previous
//
#include <hip/hip_runtime.h>
#include <cstdint>

// Problem constants: B=2, S=2048, D=2048, H=16, DH=128
typedef unsigned short u16;
typedef __attribute__((ext_vector_type(8))) short short8v;       // 8 x bf16 (MFMA A/B frag)
typedef __attribute__((ext_vector_type(8))) unsigned short u16x8;
typedef __attribute__((ext_vector_type(4))) float floatx4;       // MFMA C/D frag

typedef unsigned int __attribute__((address_space(1))) as1_u32;
typedef unsigned int __attribute__((address_space(3))) as3_u32;

__device__ __forceinline__ u16 f2bf(float f) {
  union { float f; unsigned u; } v; v.f = f;
  unsigned r = v.u + 0x7FFFu + ((v.u >> 16) & 1u);   // RNE
  return (u16)(r >> 16);
}

__device__ __forceinline__ unsigned cvt_pk_bf16(float lo, float hi) {
  unsigned r;
  asm("v_cvt_pk_bf16_f32 %0, %1, %2" : "=v"(r) : "v"(lo), "v"(hi));
  return r;
}

__device__ __forceinline__ void gload16(void* lds, const void* g) {
  __builtin_amdgcn_global_load_lds((as1_u32*)(uintptr_t)g, (as3_u32*)(uintptr_t)lds, 16, 0, 0);
}

// ---------------- fused fp32 -> bf16 conversion (3 segments, 1 launch) ----------------
__global__ __launch_bounds__(256)
void f2bf3_kernel(const float* __restrict__ in0, u16* __restrict__ out0, int n0,
                  const float* __restrict__ in1, u16* __restrict__ out1, int n1,
                  const float* __restrict__ in2, u16* __restrict__ out2, int n2) {
  int i = blockIdx.x * 256 + threadIdx.x;
  const int stride = gridDim.x * 256;
  const int total = n0 + n1 + n2;
  for (; i < total; i += stride) {
    const float* src; u16* dst; int k;
    if (i < n0)            { src = in0; dst = out0; k = i; }
    else if (i < n0 + n1)  { src = in1; dst = out1; k = i - n0; }
    else                   { src = in2; dst = out2; k = i - n0 - n1; }
    float4 v = ((const float4*)src)[k];
    ushort4 o;
    o.x = f2bf(v.x); o.y = f2bf(v.y); o.z = f2bf(v.z); o.w = f2bf(v.w);
    ((ushort4*)dst)[k] = o;
  }
}

// ---------------- QKV GEMM: 128x256 BK=32, 512 thr, 3-slot, 2 blocks/CU ----------
// (round-12/14 winner: 119 us, MfmaUtil 38%, conflicts 0)
// SPLIT_V: bcol>=4096 blocks write transposed into VT[b*16+h][dh][s].
__global__ __launch_bounds__(512, 4)
void gemm_qkv(const u16* __restrict__ A, const u16* __restrict__ B,
              const float* __restrict__ bias, u16* __restrict__ C,
              u16* __restrict__ VT, int M, int N, int K) {
  __shared__ u16 Al[3][4096];   // 24KB
  __shared__ u16 Bl[3][8192];   // 48KB
  const int tid = threadIdx.x;
  const int wid = tid >> 6, lane = tid & 63;
  const int wr = wid >> 2, wc = wid & 3;
  const int li = lane & 15, lg = lane >> 4;
  const int nwg = gridDim.x;
  const int bid = blockIdx.x;
  const int swz = (bid & 7) * (nwg >> 3) + (bid >> 3);   // XCD-bijective (nwg%8==0)
  const int mcnt = M >> 7;
  const int bm = swz % mcnt, bn = swz / mcnt;            // bm-fastest: B-panels L2-hot
  const int brow = bm * 128, bcol = bn * 256;
  const int NT = K >> 5;                                 // BK=32

  const int P = tid * 16;
  const int pr = P >> 7;
  const int innerLog = (P & 127) ^ ((pr & 7) << 4);
  const int srow = (pr << 1) + (innerLog >> 6);
  const int skb = innerLog & 63;
  const u16* aS = A + (size_t)(brow + srow) * K + (skb >> 1);
  const u16* bS = B + (size_t)(bcol + srow) * K + (skb >> 1);

#define STG(slot, kt_)                                                          \
  {                                                                             \
    const u16* a_ = aS + (kt_) * 32;                                            \
    const u16* b_ = bS + (kt_) * 32;                                            \
    gload16((char*)&Al[slot][0] + P, a_);                                       \
    gload16((char*)&Bl[slot][0] + P, b_);                                       \
    gload16((char*)&Bl[slot][0] + 8192 + P, b_ + (size_t)128 * K);              \
  }

  floatx4 acc[4][4];
#pragma unroll
  for (int m = 0; m < 4; ++m)
#pragma unroll
    for (int n = 0; n < 4; ++n) acc[m][n] = floatx4{0.f, 0.f, 0.f, 0.f};

  const int fxor = ((li >> 1) & 7) << 4;
  const int finner = (((li & 1) << 6) + (lg << 4)) ^ fxor;
  const int aoff = (wr * 32 + (li >> 1)) * 128 + finner;
  const int boff = (wc * 32 + (li >> 1)) * 128 + finner;

  STG(0, 0);
  STG(1, 1);
  asm volatile("s_waitcnt vmcnt(3)" ::: "memory");
  __builtin_amdgcn_s_barrier();

  int sl = 0;
  for (int t = 0; t < NT; ++t) {
    const char* Ab = (const char*)&Al[sl][0];
    const char* Bb = (const char*)&Bl[sl][0];
    short8v af[4], bf[4];
#pragma unroll
    for (int m = 0; m < 4; ++m) af[m] = *(const short8v*)(Ab + aoff + m * 1024);
#pragma unroll
    for (int n = 0; n < 4; ++n) bf[n] = *(const short8v*)(Bb + boff + n * 1024);

    int s2 = sl + 2; if (s2 >= 3) s2 -= 3;
    if (t + 2 < NT) STG(s2, t + 2);

    __builtin_amdgcn_s_setprio(1);
#pragma unroll
    for (int m = 0; m < 4; ++m)
#pragma unroll
      for (int n = 0; n < 4; ++n)
        acc[m][n] = __builtin_amdgcn_mfma_f32_16x16x32_bf16(af[m], bf[n], acc[m][n], 0, 0, 0);
    __builtin_amdgcn_s_setprio(0);

    if (t + 2 < NT)      asm volatile("s_waitcnt vmcnt(3)" ::: "memory");
    else if (t + 1 < NT) asm volatile("s_waitcnt vmcnt(0)" ::: "memory");
    __builtin_amdgcn_s_barrier();
    sl = (sl + 1 == 3) ? 0 : sl + 1;
  }
#undef STG

  const int crow0 = brow + wr * 64 + lg * 4;
  const int ccol0 = bcol + wc * 64 + li;
  if (bcol >= 4096) {
    // V region -> write transposed into VT[(b*16+h)*128+dh][s]
    const int bb = crow0 >> 11;          // uniform per block
    const int s0b = (crow0 & 2047);      // + m*16 (+j within ushort4)
#pragma unroll
    for (int n = 0; n < 4; ++n) {
      const int vcol = ccol0 - 4096 + n * 16;
      const int hh = vcol >> 7, dh = vcol & 127;
      const float bv = bias[ccol0 + n * 16];
      u16* drow = VT + ((size_t)(bb * 16 + hh) * 128 + dh) * 2048;
#pragma unroll
      for (int m = 0; m < 4; ++m) {
        ushort4 o;
        o.x = f2bf(acc[m][n][0] + bv);
        o.y = f2bf(acc[m][n][1] + bv);
        o.z = f2bf(acc[m][n][2] + bv);
        o.w = f2bf(acc[m][n][3] + bv);
        *(ushort4*)(drow + s0b + m * 16) = o;
      }
    }
  } else {
#pragma unroll
    for (int n = 0; n < 4; ++n) {
      const float bv = bias[ccol0 + n * 16];
#pragma unroll
      for (int m = 0; m < 4; ++m) {
#pragma unroll
        for (int j = 0; j < 4; ++j) {
          const float v = acc[m][n][j] + bv;
          C[(size_t)(crow0 + m * 16 + j) * N + (ccol0 + n * 16)] = f2bf(v);
        }
      }
    }
  }
}

// ---------------- 128x128 BK=32 GEMM, 256 thr, 3-slot, 3 blocks/CU (out-proj) ------
template <int OUT_BF16>
__global__ __launch_bounds__(256, 4)
void gemm_s(const u16* __restrict__ A, const u16* __restrict__ B,
            const float* __restrict__ bias, void* __restrict__ C,
            int M, int N, int K) {
  __shared__ u16 Al[3][4096];   // 24KB
  __shared__ u16 Bl[3][4096];   // 24KB
  const int tid = threadIdx.x;
  const int wid = tid >> 6, lane = tid & 63;
  const int wr = wid >> 1, wc = wid & 1;
  const int li = lane & 15, lg = lane >> 4;
  const int nwg = gridDim.x;
  const int bid = blockIdx.x;
  const int swz = (bid & 7) * (nwg >> 3) + (bid >> 3);   // XCD-bijective
  const int mcnt = M >> 7;
  const int bm = swz % mcnt, bn = swz / mcnt;
  const int brow = bm * 128, bcol = bn * 128;
  const int NT = K >> 5;

  const int P = tid * 16;                                 // 0..4095
  const int pr = P >> 7;
  const int innerLog = (P & 127) ^ ((pr & 7) << 4);
  const int srow = (pr << 1) + (innerLog >> 6);           // 0..63
  const int skb = innerLog & 63;
  const u16* aS = A + (size_t)(brow + srow) * K + (skb >> 1);
  const u16* bS = B + (size_t)(bcol + srow) * K + (skb >> 1);

#define STG(slot, kt_)                                                          \
  {                                                                             \
    const u16* a_ = aS + (kt_) * 32;                                            \
    const u16* b_ = bS + (kt_) * 32;                                            \
    gload16((char*)&Al[slot][0] + P, a_);                                       \
    gload16((char*)&Al[slot][0] + 4096 + P, a_ + (size_t)64 * K);               \
    gload16((char*)&Bl[slot][0] + P, b_);                                       \
    gload16((char*)&Bl[slot][0] + 4096 + P, b_ + (size_t)64 * K);               \
  }

  floatx4 acc[4][4];
#pragma unroll
  for (int m = 0; m < 4; ++m)
#pragma unroll
    for (int n = 0; n < 4; ++n) acc[m][n] = floatx4{0.f, 0.f, 0.f, 0.f};

  const int fxor = ((li >> 1) & 7) << 4;
  const int finner = (((li & 1) << 6) + (lg << 4)) ^ fxor;
  const int aoff = (wr * 32 + (li >> 1)) * 128 + finner;
  const int boff = (wc * 32 + (li >> 1)) * 128 + finner;

  STG(0, 0);
  STG(1, 1);
  asm volatile("s_waitcnt vmcnt(4)" ::: "memory");
  __builtin_amdgcn_s_barrier();

  int sl = 0;
  for (int t = 0; t < NT; ++t) {
    const char* Ab = (const char*)&Al[sl][0];
    const char* Bb = (const char*)&Bl[sl][0];
    short8v af[4], bf[4];
#pragma unroll
    for (int m = 0; m < 4; ++m) af[m] = *(const short8v*)(Ab + aoff + m * 1024);
#pragma unroll
    for (int n = 0; n < 4; ++n) bf[n] = *(const short8v*)(Bb + boff + n * 1024);

    int s2 = sl + 2; if (s2 >= 3) s2 -= 3;
    if (t + 2 < NT) STG(s2, t + 2);

    __builtin_amdgcn_s_setprio(1);
#pragma unroll
    for (int m = 0; m < 4; ++m)
#pragma unroll
      for (int n = 0; n < 4; ++n)
        acc[m][n] = __builtin_amdgcn_mfma_f32_16x16x32_bf16(af[m], bf[n], acc[m][n], 0, 0, 0);
    __builtin_amdgcn_s_setprio(0);

    if (t + 2 < NT)      asm volatile("s_waitcnt vmcnt(4)" ::: "memory");
    else if (t + 1 < NT) asm volatile("s_waitcnt vmcnt(0)" ::: "memory");
    __builtin_amdgcn_s_barrier();
    sl = (sl + 1 == 3) ? 0 : sl + 1;
  }
#undef STG

  const int crow0 = brow + wr * 64 + lg * 4;
  const int ccol0 = bcol + wc * 64 + li;
#pragma unroll
  for (int n = 0; n < 4; ++n) {
    const float bv = bias[ccol0 + n * 16];
#pragma unroll
    for (int m = 0; m < 4; ++m) {
#pragma unroll
      for (int j = 0; j < 4; ++j) {
        const float v = acc[m][n][j] + bv;
        const size_t idx = (size_t)(crow0 + m * 16 + j) * N + (ccol0 + n * 16);
        if (OUT_BF16) ((u16*)C)[idx] = f2bf(v);
        else          ((float*)C)[idx] = v;
      }
    }
  }
}

// ---------------- fused causal flash attention (round-8 structure + T5 setprio) ----
__global__ __launch_bounds__(256, 2)
void attn_fused(const u16* __restrict__ qkv, const u16* __restrict__ vt,
                const int* __restrict__ kpm, u16* __restrict__ attn_out) {
  constexpr int S = 2048, DQ = 6144;
  __shared__ u16 Kl[2][64 * 128];   // 32KB, double-buffered; reused as O-staging
  __shared__ u16 Vl[128 * 64];      // 16KB
  __shared__ float mskf[2048];      // 8KB additive pad penalties
  __shared__ int s_any;
  const int bx = blockIdx.x, by = blockIdx.y;
  const int qt = ((by >> 4) & 1) ? bx : (15 - bx);   // co-resident qt balance
  const int bh = by;
  const int b = bh >> 4, h = bh & 15;
  const int tid = threadIdx.x, wave = tid >> 6, lane = tid & 63;
  const int lg = lane >> 4, li = lane & 15;
  const int qrow0 = qt * 128 + wave * 32;

  const u16* Qb = qkv + (size_t)b * S * DQ + h * 128;
  const u16* Kb = Qb + 2048;
  const u16* Vtb = vt + (size_t)bh * 128 * 2048;
  const int* mrow = kpm + b * S;

  if (tid == 0) s_any = 0;
  __syncthreads();
  {
    int a = 0;
    for (int j = tid; j < 2048; j += 256) {
      const int mv = mrow[j];
      mskf[j] = mv ? 0.f : -1.0e9f;
      if (mv && j <= qt * 128) a = 1;
    }
    if (a) s_any = 1;
  }
  __syncthreads();
  const int anyv = s_any;
  const int nt = anyv ? (2 * qt + 2) : 32;
  const int causalFromW = anyv ? (qrow0 >> 6) : 0;

  short8v qb[2][4];
#pragma unroll
  for (int m = 0; m < 2; ++m) {
    const u16* qp = Qb + (size_t)(qrow0 + m * 16 + li) * DQ + lg * 8;
#pragma unroll
    for (int kk = 0; kk < 4; ++kk) qb[m][kk] = *(const short8v*)(qp + kk * 32);
  }
  asm volatile("s_waitcnt vmcnt(0)" ::: "memory");  // clean VMEM ledger

  float mM[2], lSum[2];
  floatx4 oa[2][8];
#pragma unroll
  for (int m = 0; m < 2; ++m) {
    mM[m] = -3.0e38f; lSum[m] = 0.f;
#pragma unroll
    for (int n = 0; n < 8; ++n) oa[m][n] = floatx4{0.f, 0.f, 0.f, 0.f};
  }

  const u16* kSrc[4]; const u16* vSrc[4];
#pragma unroll
  for (int i = 0; i < 4; ++i) {
    const int L = i * 4096 + tid * 16;
    const int r = L >> 8;
    const int c = ((L & 255) ^ ((r & 7) << 4)) >> 1;
    kSrc[i] = Kb + (size_t)r * DQ + c;
    const int d = L >> 7;
    const int sv = ((L & 127) ^ ((d & 7) << 4)) >> 1;
    vSrc[i] = Vtb + (size_t)d * 2048 + sv;
  }

#define STAGE_K(buf, kt_)                                                      \
  {                                                                            \
    const int kv0_ = (kt_) * 64;                                               \
    _Pragma("unroll")                                                          \
    for (int i = 0; i < 4; ++i)                                                \
      gload16((char*)Kl + (buf) * 16384 + i * 4096 + tid * 16,                 \
              kSrc[i] + (size_t)kv0_ * DQ);                                    \
  }
#define STAGE_V(kt_)                                                           \
  {                                                                            \
    const int kv0_ = (kt_) * 64;                                               \
    _Pragma("unroll")                                                          \
    for (int i = 0; i < 4; ++i)                                                \
      gload16((char*)Vl + i * 4096 + tid * 16, vSrc[i] + kv0_);                \
  }

  const float scale = 0.08838834764831845f;  // 1/sqrt(128)

  STAGE_K(0, 0);
  STAGE_V(0);

  for (int kt = 0; kt < nt; ++kt) {
    const int cur = kt & 1;
    const int kv0 = kt * 64;
    if (kt + 1 < nt) {
      STAGE_K(cur ^ 1, kt + 1);
      asm volatile("s_waitcnt vmcnt(8)" ::: "memory");
    } else {
      asm volatile("s_waitcnt vmcnt(4)" ::: "memory");
    }
    __builtin_amdgcn_s_barrier();

    const char* Kcur = (const char*)Kl + cur * 16384;

    floatx4 sc[2][4];
#pragma unroll
    for (int n = 0; n < 4; ++n) { sc[0][n] = floatx4{0,0,0,0}; sc[1][n] = floatx4{0,0,0,0}; }
    __builtin_amdgcn_s_setprio(1);
#pragma unroll
    for (int n = 0; n < 4; ++n) {
      const int r = n * 16 + li;
#pragma unroll
      for (int kk = 0; kk < 4; ++kk) {
        const int byteo = (r * 256 + kk * 64 + lg * 16) ^ ((r & 7) << 4);
        const short8v kf = *(const short8v*)(Kcur + byteo);
        sc[0][n] = __builtin_amdgcn_mfma_f32_16x16x32_bf16(kf, qb[0][kk], sc[0][n], 0, 0, 0);
        sc[1][n] = __builtin_amdgcn_mfma_f32_16x16x32_bf16(kf, qb[1][kk], sc[1][n], 0, 0, 0);
      }
    }
    __builtin_amdgcn_s_setprio(0);

    floatx4 pbv[4];
#pragma unroll
    for (int n = 0; n < 4; ++n)
      pbv[n] = *(const floatx4*)&mskf[kv0 + n * 16 + lg * 4];
    const bool cz = (kt >= causalFromW);

    short8v pf[2][2];
#pragma unroll
    for (int m = 0; m < 2; ++m) {
      const int q_l = qrow0 + m * 16 + li;
      float tmax = -3.0e38f;
#pragma unroll
      for (int n = 0; n < 4; ++n)
#pragma unroll
        for (int j = 0; j < 4; ++j) {
          float s = sc[m][n][j] * scale + pbv[n][j];
          if (cz && (kv0 + n * 16 + lg * 4 + j > q_l)) s -= 1.0e9f;
          sc[m][n][j] = s;
          tmax = fmaxf(tmax, s);
        }
      tmax = fmaxf(tmax, __shfl_xor(tmax, 16));
      tmax = fmaxf(tmax, __shfl_xor(tmax, 32));
      const float mnew = fmaxf(mM[m], tmax);
      const float f = __expf(mM[m] - mnew);
      mM[m] = mnew;
      float rs = 0.f;
#pragma unroll
      for (int n = 0; n < 4; ++n)
#pragma unroll
        for (int j = 0; j < 4; ++j) {
          const float e = __expf(sc[m][n][j] - mnew);
          sc[m][n][j] = e; rs += e;
        }
      rs += __shfl_xor(rs, 16);
      rs += __shfl_xor(rs, 32);
      lSum[m] = lSum[m] * f + rs;
#pragma unroll
      for (int n2 = 0; n2 < 8; ++n2) oa[m][n2] *= f;

      unsigned w32[4][2];
#pragma unroll
      for (int n = 0; n < 4; ++n) {
        w32[n][0] = cvt_pk_bf16(sc[m][n][0], sc[m][n][1]);
        w32[n][1] = cvt_pk_bf16(sc[m][n][2], sc[m][n][3]);
      }
      union PF { short8v s; unsigned w[4]; } pfu[2];
#pragma unroll
      for (int kk2 = 0; kk2 < 2; ++kk2) {
#pragma unroll
        for (int hh = 0; hh < 2; ++hh) {
          unsigned u = w32[2 * kk2][hh], v = w32[2 * kk2 + 1][hh];
          asm volatile("v_permlane32_swap_b32 %0, %1" : "+v"(u), "+v"(v));
          asm volatile("v_permlane16_swap_b32 %0, %1" : "+v"(u), "+v"(v));
          pfu[kk2].w[hh] = u;
          pfu[kk2].w[2 + hh] = v;
        }
      }
      pf[m][0] = pfu[0].s;
      pf[m][1] = pfu[1].s;
    }

    if (kt + 1 < nt) asm volatile("s_waitcnt vmcnt(4)" ::: "memory");
    else             asm volatile("s_waitcnt vmcnt(0)" ::: "memory");
    __builtin_amdgcn_s_barrier();

    __builtin_amdgcn_s_setprio(1);
#pragma unroll
    for (int kk2 = 0; kk2 < 2; ++kk2) {
#pragma unroll
      for (int n2 = 0; n2 < 8; ++n2) {
        const int d = n2 * 16 + li;
        const int vbyte = (d * 128 + kk2 * 64 + lg * 16) ^ ((d & 7) << 4);
        const short8v vf = *(const short8v*)((const char*)Vl + vbyte);
        oa[0][n2] = __builtin_amdgcn_mfma_f32_16x16x32_bf16(vf, pf[0][kk2], oa[0][n2], 0, 0, 0);
        oa[1][n2] = __builtin_amdgcn_mfma_f32_16x16x32_bf16(vf, pf[1][kk2], oa[1][n2], 0, 0, 0);
      }
    }
    __builtin_amdgcn_s_setprio(0);
    __builtin_amdgcn_s_barrier();
    if (kt + 1 < nt) STAGE_V(kt + 1);
  }

  {
    char* Ol = (char*)Kl + wave * 8192;
#pragma unroll
    for (int m = 0; m < 2; ++m) {
      const float inv = 1.0f / lSum[m];
      const int q_ = m * 16 + li;
#pragma unroll
      for (int n2 = 0; n2 < 8; ++n2) {
        unsigned lo = cvt_pk_bf16(oa[m][n2][0] * inv, oa[m][n2][1] * inv);
        unsigned hi = cvt_pk_bf16(oa[m][n2][2] * inv, oa[m][n2][3] * inv);
        const int byteo = (q_ * 256 + n2 * 32 + lg * 8) ^ ((q_ & 7) << 4);
        uint2 pr2; pr2.x = lo; pr2.y = hi;
        *(uint2*)(Ol + byteo) = pr2;
      }
    }
    asm volatile("s_waitcnt lgkmcnt(0)" ::: "memory");
#pragma unroll
    for (int rr = 0; rr < 4; ++rr) {
      const int r = rr * 8 + (lane >> 3);
      const size_t grow = (size_t)(b * 2048 + qt * 128 + wave * 32 + r) * 2048 + h * 128;
#pragma unroll
      for (int s2 = 0; s2 < 2; ++s2) {
        const int byteo = (r * 256 + (lane & 7) * 32 + s2 * 16) ^ ((r & 7) << 4);
        const u16x8 val = *(const u16x8*)(Ol + byteo);
        *(u16x8*)&attn_out[grow + (lane & 7) * 16 + s2 * 8] = val;
      }
    }
  }
#undef STAGE_K
#undef STAGE_V
}

// ---------------- launch ----------------
extern "C" void kernel_launch(void* const* d_in, const int* in_sizes, int n_in,
                              void* d_out, int out_size, void* d_ws, size_t ws_size,
                              hipStream_t stream) {
  const float* x    = (const float*)d_in[0];   // [2,2048,2048]
  const int*   kpm  = (const int*)d_in[1];     // [2,2048]
  const float* wqkv = (const float*)d_in[2];   // [6144,2048]
  const float* bqkv = (const float*)d_in[3];   // [6144]
  const float* wout = (const float*)d_in[4];   // [2048,2048]
  const float* bout = (const float*)d_in[5];   // [2048]
  float* out = (float*)d_out;

  char* ws = (char*)d_ws;
  u16* xbf   = (u16*)(ws);                    // 16 MiB: x bf16 [4096,2048]
  u16* wqbf  = (u16*)(ws + (16u << 20));      // 24 MiB: Wqkv bf16 [6144,2048]
  u16* wobf  = (u16*)(ws + (40u << 20));      //  8 MiB: out_w bf16 [2048,2048]
  u16* qkvb  = (u16*)(ws + (48u << 20));      // 48 MiB: qkv bf16 [4096,6144] (V third unused)
  u16* vtb   = (u16*)(ws + (96u << 20));      // 16 MiB: V^T bf16 [32,128,2048]
  u16* attnb = (u16*)(ws + (112u << 20));     // 16 MiB: attn bf16 [4096,2048]

  f2bf3_kernel<<<2048, 256, 0, stream>>>(x,    xbf,  4096 * 2048 / 4,
                                         wqkv, wqbf, 6144 * 2048 / 4,
                                         wout, wobf, 2048 * 2048 / 4);

  gemm_qkv<<<768, 512, 0, stream>>>(xbf, wqbf, bqkv, qkvb, vtb, 4096, 6144, 2048);
  attn_fused<<<dim3(16, 32), 256, 0, stream>>>(qkvb, vtb, kpm, attnb);
  gemm_s<0><<<512, 256, 0, stream>>>(attnb, wobf, bout, out, 4096, 2048, 2048);
}

// Round 17
// 276.673 us; speedup vs baseline: 1.0915x; 1.0117x over previous
//
#include <hip/hip_runtime.h>
#include <cstdint>

// Problem constants: B=2, S=2048, D=2048, H=16, DH=128
typedef unsigned short u16;
typedef __attribute__((ext_vector_type(8))) short short8v;       // 8 x bf16 (MFMA A/B frag)
typedef __attribute__((ext_vector_type(8))) unsigned short u16x8;
typedef __attribute__((ext_vector_type(4))) float floatx4;       // MFMA C/D frag

typedef unsigned int __attribute__((address_space(1))) as1_u32;
typedef unsigned int __attribute__((address_space(3))) as3_u32;

__device__ __forceinline__ u16 f2bf(float f) {
  union { float f; unsigned u; } v; v.f = f;
  unsigned r = v.u + 0x7FFFu + ((v.u >> 16) & 1u);   // RNE
  return (u16)(r >> 16);
}

__device__ __forceinline__ unsigned cvt_pk_bf16(float lo, float hi) {
  unsigned r;
  asm("v_cvt_pk_bf16_f32 %0, %1, %2" : "=v"(r) : "v"(lo), "v"(hi));
  return r;
}

__device__ __forceinline__ float exp2_raw(float x) {   // 2^x, single v_exp_f32
  float r;
  asm("v_exp_f32 %0, %1" : "=v"(r) : "v"(x));
  return r;
}

__device__ __forceinline__ void gload16(void* lds, const void* g) {
  __builtin_amdgcn_global_load_lds((as1_u32*)(uintptr_t)g, (as3_u32*)(uintptr_t)lds, 16, 0, 0);
}

// ---------------- fused fp32 -> bf16 conversion (3 segments, 1 launch) ----------------
__global__ __launch_bounds__(256)
void f2bf3_kernel(const float* __restrict__ in0, u16* __restrict__ out0, int n0,
                  const float* __restrict__ in1, u16* __restrict__ out1, int n1,
                  const float* __restrict__ in2, u16* __restrict__ out2, int n2) {
  int i = blockIdx.x * 256 + threadIdx.x;
  const int stride = gridDim.x * 256;
  const int total = n0 + n1 + n2;
  for (; i < total; i += stride) {
    const float* src; u16* dst; int k;
    if (i < n0)            { src = in0; dst = out0; k = i; }
    else if (i < n0 + n1)  { src = in1; dst = out1; k = i - n0; }
    else                   { src = in2; dst = out2; k = i - n0 - n1; }
    float4 v = ((const float4*)src)[k];
    ushort4 o;
    o.x = f2bf(v.x); o.y = f2bf(v.y); o.z = f2bf(v.z); o.w = f2bf(v.w);
    ((ushort4*)dst)[k] = o;
  }
}

// ---------------- QKV GEMM: 128x256 BK=32, 512 thr, 3-slot, 2 blocks/CU ----------
// (round-12/14/16 winner: ~119 us, MfmaUtil 38%, conflicts 0) — UNCHANGED.
__global__ __launch_bounds__(512, 4)
void gemm_qkv(const u16* __restrict__ A, const u16* __restrict__ B,
              const float* __restrict__ bias, u16* __restrict__ C,
              u16* __restrict__ VT, int M, int N, int K) {
  __shared__ u16 Al[3][4096];   // 24KB
  __shared__ u16 Bl[3][8192];   // 48KB
  const int tid = threadIdx.x;
  const int wid = tid >> 6, lane = tid & 63;
  const int wr = wid >> 2, wc = wid & 3;
  const int li = lane & 15, lg = lane >> 4;
  const int nwg = gridDim.x;
  const int bid = blockIdx.x;
  const int swz = (bid & 7) * (nwg >> 3) + (bid >> 3);   // XCD-bijective (nwg%8==0)
  const int mcnt = M >> 7;
  const int bm = swz % mcnt, bn = swz / mcnt;            // bm-fastest: B-panels L2-hot
  const int brow = bm * 128, bcol = bn * 256;
  const int NT = K >> 5;                                 // BK=32

  const int P = tid * 16;
  const int pr = P >> 7;
  const int innerLog = (P & 127) ^ ((pr & 7) << 4);
  const int srow = (pr << 1) + (innerLog >> 6);
  const int skb = innerLog & 63;
  const u16* aS = A + (size_t)(brow + srow) * K + (skb >> 1);
  const u16* bS = B + (size_t)(bcol + srow) * K + (skb >> 1);

#define STG(slot, kt_)                                                          \
  {                                                                             \
    const u16* a_ = aS + (kt_) * 32;                                            \
    const u16* b_ = bS + (kt_) * 32;                                            \
    gload16((char*)&Al[slot][0] + P, a_);                                       \
    gload16((char*)&Bl[slot][0] + P, b_);                                       \
    gload16((char*)&Bl[slot][0] + 8192 + P, b_ + (size_t)128 * K);              \
  }

  floatx4 acc[4][4];
#pragma unroll
  for (int m = 0; m < 4; ++m)
#pragma unroll
    for (int n = 0; n < 4; ++n) acc[m][n] = floatx4{0.f, 0.f, 0.f, 0.f};

  const int fxor = ((li >> 1) & 7) << 4;
  const int finner = (((li & 1) << 6) + (lg << 4)) ^ fxor;
  const int aoff = (wr * 32 + (li >> 1)) * 128 + finner;
  const int boff = (wc * 32 + (li >> 1)) * 128 + finner;

  STG(0, 0);
  STG(1, 1);
  asm volatile("s_waitcnt vmcnt(3)" ::: "memory");
  __builtin_amdgcn_s_barrier();

  int sl = 0;
  for (int t = 0; t < NT; ++t) {
    const char* Ab = (const char*)&Al[sl][0];
    const char* Bb = (const char*)&Bl[sl][0];
    short8v af[4], bf[4];
#pragma unroll
    for (int m = 0; m < 4; ++m) af[m] = *(const short8v*)(Ab + aoff + m * 1024);
#pragma unroll
    for (int n = 0; n < 4; ++n) bf[n] = *(const short8v*)(Bb + boff + n * 1024);

    int s2 = sl + 2; if (s2 >= 3) s2 -= 3;
    if (t + 2 < NT) STG(s2, t + 2);

    __builtin_amdgcn_s_setprio(1);
#pragma unroll
    for (int m = 0; m < 4; ++m)
#pragma unroll
      for (int n = 0; n < 4; ++n)
        acc[m][n] = __builtin_amdgcn_mfma_f32_16x16x32_bf16(af[m], bf[n], acc[m][n], 0, 0, 0);
    __builtin_amdgcn_s_setprio(0);

    if (t + 2 < NT)      asm volatile("s_waitcnt vmcnt(3)" ::: "memory");
    else if (t + 1 < NT) asm volatile("s_waitcnt vmcnt(0)" ::: "memory");
    __builtin_amdgcn_s_barrier();
    sl = (sl + 1 == 3) ? 0 : sl + 1;
  }
#undef STG

  const int crow0 = brow + wr * 64 + lg * 4;
  const int ccol0 = bcol + wc * 64 + li;
  if (bcol >= 4096) {
    const int bb = crow0 >> 11;          // uniform per block
    const int s0b = (crow0 & 2047);      // + m*16 (+j within ushort4)
#pragma unroll
    for (int n = 0; n < 4; ++n) {
      const int vcol = ccol0 - 4096 + n * 16;
      const int hh = vcol >> 7, dh = vcol & 127;
      const float bv = bias[ccol0 + n * 16];
      u16* drow = VT + ((size_t)(bb * 16 + hh) * 128 + dh) * 2048;
#pragma unroll
      for (int m = 0; m < 4; ++m) {
        ushort4 o;
        o.x = f2bf(acc[m][n][0] + bv);
        o.y = f2bf(acc[m][n][1] + bv);
        o.z = f2bf(acc[m][n][2] + bv);
        o.w = f2bf(acc[m][n][3] + bv);
        *(ushort4*)(drow + s0b + m * 16) = o;
      }
    }
  } else {
#pragma unroll
    for (int n = 0; n < 4; ++n) {
      const float bv = bias[ccol0 + n * 16];
#pragma unroll
      for (int m = 0; m < 4; ++m) {
#pragma unroll
        for (int j = 0; j < 4; ++j) {
          const float v = acc[m][n][j] + bv;
          C[(size_t)(crow0 + m * 16 + j) * N + (ccol0 + n * 16)] = f2bf(v);
        }
      }
    }
  }
}

// ---------------- 128x128 BK=32 GEMM, 256 thr, 3-slot, 3 blocks/CU (out-proj) ------
template <int OUT_BF16>
__global__ __launch_bounds__(256, 4)
void gemm_s(const u16* __restrict__ A, const u16* __restrict__ B,
            const float* __restrict__ bias, void* __restrict__ C,
            int M, int N, int K) {
  __shared__ u16 Al[3][4096];   // 24KB
  __shared__ u16 Bl[3][4096];   // 24KB
  const int tid = threadIdx.x;
  const int wid = tid >> 6, lane = tid & 63;
  const int wr = wid >> 1, wc = wid & 1;
  const int li = lane & 15, lg = lane >> 4;
  const int nwg = gridDim.x;
  const int bid = blockIdx.x;
  const int swz = (bid & 7) * (nwg >> 3) + (bid >> 3);   // XCD-bijective
  const int mcnt = M >> 7;
  const int bm = swz % mcnt, bn = swz / mcnt;
  const int brow = bm * 128, bcol = bn * 128;
  const int NT = K >> 5;

  const int P = tid * 16;                                 // 0..4095
  const int pr = P >> 7;
  const int innerLog = (P & 127) ^ ((pr & 7) << 4);
  const int srow = (pr << 1) + (innerLog >> 6);           // 0..63
  const int skb = innerLog & 63;
  const u16* aS = A + (size_t)(brow + srow) * K + (skb >> 1);
  const u16* bS = B + (size_t)(bcol + srow) * K + (skb >> 1);

#define STG(slot, kt_)                                                          \
  {                                                                             \
    const u16* a_ = aS + (kt_) * 32;                                            \
    const u16* b_ = bS + (kt_) * 32;                                            \
    gload16((char*)&Al[slot][0] + P, a_);                                       \
    gload16((char*)&Al[slot][0] + 4096 + P, a_ + (size_t)64 * K);               \
    gload16((char*)&Bl[slot][0] + P, b_);                                       \
    gload16((char*)&Bl[slot][0] + 4096 + P, b_ + (size_t)64 * K);               \
  }

  floatx4 acc[4][4];
#pragma unroll
  for (int m = 0; m < 4; ++m)
#pragma unroll
    for (int n = 0; n < 4; ++n) acc[m][n] = floatx4{0.f, 0.f, 0.f, 0.f};

  const int fxor = ((li >> 1) & 7) << 4;
  const int finner = (((li & 1) << 6) + (lg << 4)) ^ fxor;
  const int aoff = (wr * 32 + (li >> 1)) * 128 + finner;
  const int boff = (wc * 32 + (li >> 1)) * 128 + finner;

  STG(0, 0);
  STG(1, 1);
  asm volatile("s_waitcnt vmcnt(4)" ::: "memory");
  __builtin_amdgcn_s_barrier();

  int sl = 0;
  for (int t = 0; t < NT; ++t) {
    const char* Ab = (const char*)&Al[sl][0];
    const char* Bb = (const char*)&Bl[sl][0];
    short8v af[4], bf[4];
#pragma unroll
    for (int m = 0; m < 4; ++m) af[m] = *(const short8v*)(Ab + aoff + m * 1024);
#pragma unroll
    for (int n = 0; n < 4; ++n) bf[n] = *(const short8v*)(Bb + boff + n * 1024);

    int s2 = sl + 2; if (s2 >= 3) s2 -= 3;
    if (t + 2 < NT) STG(s2, t + 2);

    __builtin_amdgcn_s_setprio(1);
#pragma unroll
    for (int m = 0; m < 4; ++m)
#pragma unroll
      for (int n = 0; n < 4; ++n)
        acc[m][n] = __builtin_amdgcn_mfma_f32_16x16x32_bf16(af[m], bf[n], acc[m][n], 0, 0, 0);
    __builtin_amdgcn_s_setprio(0);

    if (t + 2 < NT)      asm volatile("s_waitcnt vmcnt(4)" ::: "memory");
    else if (t + 1 < NT) asm volatile("s_waitcnt vmcnt(0)" ::: "memory");
    __builtin_amdgcn_s_barrier();
    sl = (sl + 1 == 3) ? 0 : sl + 1;
  }
#undef STG

  const int crow0 = brow + wr * 64 + lg * 4;
  const int ccol0 = bcol + wc * 64 + li;
#pragma unroll
  for (int n = 0; n < 4; ++n) {
    const float bv = bias[ccol0 + n * 16];
#pragma unroll
    for (int m = 0; m < 4; ++m) {
#pragma unroll
      for (int j = 0; j < 4; ++j) {
        const float v = acc[m][n][j] + bv;
        const size_t idx = (size_t)(crow0 + m * 16 + j) * N + (ccol0 + n * 16);
        if (OUT_BF16) ((u16*)C)[idx] = f2bf(v);
        else          ((float*)C)[idx] = v;
      }
    }
  }
}

// ---------------- fused causal flash attention (2-barrier, V-dbuf, exp2 softmax) ----
// r8 structure with a ledger-exact simplification: V double-buffered and staged
// TOGETHER with K at the top. Per tile: {issue K(t+1)+V(t+1) (8 loads);
// vmcnt(8) = drains exactly K(t)+V(t), keeps t+1 in flight (counted, never 0);
// barrier; QK^T; softmax; PV; barrier}. 3->2 barriers, 2->1 waits per tile, and
// V gets a full iteration of latency cover. Softmax in exp2 domain: scale/pad/
// causal constants pre-multiplied by log2(e); raw v_exp_f32 (= 2^x). Degenerate
// rows still collapse exactly (|s2| << ULP(1.44e9)=128) -> uniform weights.
__global__ __launch_bounds__(256, 2)
void attn_fused(const u16* __restrict__ qkv, const u16* __restrict__ vt,
                const int* __restrict__ kpm, u16* __restrict__ attn_out) {
  constexpr int S = 2048, DQ = 6144;
  __shared__ u16 Kl[2][64 * 128];   // 32KB dbuf; reused as O-staging in epilogue
  __shared__ u16 Vl[2][64 * 128];   // 32KB dbuf ([128 d][64 k] per slot)
  __shared__ float mskf[2048];      // 8KB additive pad penalties (log2 domain)
  __shared__ int s_any;
  const int bx = blockIdx.x, by = blockIdx.y;
  const int qt = ((by >> 4) & 1) ? bx : (15 - bx);   // co-resident qt balance
  const int bh = by;
  const int b = bh >> 4, h = bh & 15;
  const int tid = threadIdx.x, wave = tid >> 6, lane = tid & 63;
  const int lg = lane >> 4, li = lane & 15;
  const int qrow0 = qt * 128 + wave * 32;

  const u16* Qb = qkv + (size_t)b * S * DQ + h * 128;
  const u16* Kb = Qb + 2048;
  const u16* Vtb = vt + (size_t)bh * 128 * 2048;
  const int* mrow = kpm + b * S;

  if (tid == 0) s_any = 0;
  __syncthreads();
  {
    int a = 0;
    for (int j = tid; j < 2048; j += 256) {
      const int mv = mrow[j];
      mskf[j] = mv ? 0.f : -1.4426950e9f;     // -1e9 * log2(e)
      if (mv && j <= qt * 128) a = 1;
    }
    if (a) s_any = 1;
  }
  __syncthreads();
  const int anyv = s_any;
  const int nt = anyv ? (2 * qt + 2) : 32;
  const int causalFromW = anyv ? (qrow0 >> 6) : 0;

  short8v qb[2][4];
#pragma unroll
  for (int m = 0; m < 2; ++m) {
    const u16* qp = Qb + (size_t)(qrow0 + m * 16 + li) * DQ + lg * 8;
#pragma unroll
    for (int kk = 0; kk < 4; ++kk) qb[m][kk] = *(const short8v*)(qp + kk * 32);
  }
  asm volatile("s_waitcnt vmcnt(0)" ::: "memory");  // clean VMEM ledger

  float mM[2], lSum[2];
  floatx4 oa[2][8];
#pragma unroll
  for (int m = 0; m < 2; ++m) {
    mM[m] = -3.0e38f; lSum[m] = 0.f;
#pragma unroll
    for (int n = 0; n < 8; ++n) oa[m][n] = floatx4{0.f, 0.f, 0.f, 0.f};
  }

  // pre-swizzled staging sources (XOR involution on bits 4-6 within a row)
  const u16* kSrc[4]; const u16* vSrc[4];
#pragma unroll
  for (int i = 0; i < 4; ++i) {
    const int L = i * 4096 + tid * 16;
    const int r = L >> 8;
    const int c = ((L & 255) ^ ((r & 7) << 4)) >> 1;
    kSrc[i] = Kb + (size_t)r * DQ + c;
    const int d = L >> 7;
    const int sv = ((L & 127) ^ ((d & 7) << 4)) >> 1;
    vSrc[i] = Vtb + (size_t)d * 2048 + sv;
  }

#define STAGE_KV(buf, kt_)                                                     \
  {                                                                            \
    const int kv0_ = (kt_) * 64;                                               \
    _Pragma("unroll")                                                          \
    for (int i = 0; i < 4; ++i)                                                \
      gload16((char*)Kl + (buf) * 16384 + i * 4096 + tid * 16,                 \
              kSrc[i] + (size_t)kv0_ * DQ);                                    \
    _Pragma("unroll")                                                          \
    for (int i = 0; i < 4; ++i)                                                \
      gload16((char*)Vl + (buf) * 16384 + i * 4096 + tid * 16,                 \
              vSrc[i] + kv0_);                                                 \
  }

  const float scale2 = 0.12751743f;   // (1/sqrt(128)) * log2(e)

  STAGE_KV(0, 0);

  for (int kt = 0; kt < nt; ++kt) {
    const int cur = kt & 1;
    const int kv0 = kt * 64;
    if (kt + 1 < nt) {
      STAGE_KV(cur ^ 1, kt + 1);
      asm volatile("s_waitcnt vmcnt(8)" ::: "memory");   // K(t)+V(t) landed
    } else {
      asm volatile("s_waitcnt vmcnt(0)" ::: "memory");
    }
    __builtin_amdgcn_s_barrier();

    const char* Kcur = (const char*)Kl + cur * 16384;
    const char* Vcur = (const char*)Vl + cur * 16384;

    floatx4 sc[2][4];
#pragma unroll
    for (int n = 0; n < 4; ++n) { sc[0][n] = floatx4{0,0,0,0}; sc[1][n] = floatx4{0,0,0,0}; }
    __builtin_amdgcn_s_setprio(1);
#pragma unroll
    for (int n = 0; n < 4; ++n) {
      const int r = n * 16 + li;
#pragma unroll
      for (int kk = 0; kk < 4; ++kk) {
        const int byteo = (r * 256 + kk * 64 + lg * 16) ^ ((r & 7) << 4);
        const short8v kf = *(const short8v*)(Kcur + byteo);
        sc[0][n] = __builtin_amdgcn_mfma_f32_16x16x32_bf16(kf, qb[0][kk], sc[0][n], 0, 0, 0);
        sc[1][n] = __builtin_amdgcn_mfma_f32_16x16x32_bf16(kf, qb[1][kk], sc[1][n], 0, 0, 0);
      }
    }
    __builtin_amdgcn_s_setprio(0);

    floatx4 pbv[4];
#pragma unroll
    for (int n = 0; n < 4; ++n)
      pbv[n] = *(const floatx4*)&mskf[kv0 + n * 16 + lg * 4];
    const bool cz = (kt >= causalFromW);

    short8v pf[2][2];
#pragma unroll
    for (int m = 0; m < 2; ++m) {
      const int q_l = qrow0 + m * 16 + li;
      float tmax = -3.0e38f;
#pragma unroll
      for (int n = 0; n < 4; ++n)
#pragma unroll
        for (int j = 0; j < 4; ++j) {
          float s = sc[m][n][j] * scale2 + pbv[n][j];
          if (cz && (kv0 + n * 16 + lg * 4 + j > q_l)) s -= 1.4426950e9f;
          sc[m][n][j] = s;
          tmax = fmaxf(tmax, s);
        }
      tmax = fmaxf(tmax, __shfl_xor(tmax, 16));
      tmax = fmaxf(tmax, __shfl_xor(tmax, 32));
      const float mnew = fmaxf(mM[m], tmax);
      const float f = exp2_raw(mM[m] - mnew);
      mM[m] = mnew;
      float rs = 0.f;
#pragma unroll
      for (int n = 0; n < 4; ++n)
#pragma unroll
        for (int j = 0; j < 4; ++j) {
          const float e = exp2_raw(sc[m][n][j] - mnew);
          sc[m][n][j] = e; rs += e;
        }
      rs += __shfl_xor(rs, 16);
      rs += __shfl_xor(rs, 32);
      lSum[m] = lSum[m] * f + rs;
#pragma unroll
      for (int n2 = 0; n2 < 8; ++n2) oa[m][n2] *= f;

      unsigned w32[4][2];
#pragma unroll
      for (int n = 0; n < 4; ++n) {
        w32[n][0] = cvt_pk_bf16(sc[m][n][0], sc[m][n][1]);
        w32[n][1] = cvt_pk_bf16(sc[m][n][2], sc[m][n][3]);
      }
      union PF { short8v s; unsigned w[4]; } pfu[2];
#pragma unroll
      for (int kk2 = 0; kk2 < 2; ++kk2) {
#pragma unroll
        for (int hh = 0; hh < 2; ++hh) {
          unsigned u = w32[2 * kk2][hh], v = w32[2 * kk2 + 1][hh];
          asm volatile("v_permlane32_swap_b32 %0, %1" : "+v"(u), "+v"(v));
          asm volatile("v_permlane16_swap_b32 %0, %1" : "+v"(u), "+v"(v));
          pfu[kk2].w[hh] = u;
          pfu[kk2].w[2 + hh] = v;
        }
      }
      pf[m][0] = pfu[0].s;
      pf[m][1] = pfu[1].s;
    }

    __builtin_amdgcn_s_setprio(1);
#pragma unroll
    for (int kk2 = 0; kk2 < 2; ++kk2) {
#pragma unroll
      for (int n2 = 0; n2 < 8; ++n2) {
        const int d = n2 * 16 + li;
        const int vbyte = (d * 128 + kk2 * 64 + lg * 16) ^ ((d & 7) << 4);
        const short8v vf = *(const short8v*)(Vcur + vbyte);
        oa[0][n2] = __builtin_amdgcn_mfma_f32_16x16x32_bf16(vf, pf[0][kk2], oa[0][n2], 0, 0, 0);
        oa[1][n2] = __builtin_amdgcn_mfma_f32_16x16x32_bf16(vf, pf[1][kk2], oa[1][n2], 0, 0, 0);
      }
    }
    __builtin_amdgcn_s_setprio(0);
    __builtin_amdgcn_s_barrier();   // all reads of slot cur done before next overwrite
  }

  // epilogue: oa[m][n2][j] = O[q=qrow0+m*16+li][d=n2*16+lg*4+j]; stage in Kl, coalesce
  {
    char* Ol = (char*)Kl + wave * 8192;   // [32 q][128 d] u16, swizzled
#pragma unroll
    for (int m = 0; m < 2; ++m) {
      const float inv = 1.0f / lSum[m];
      const int q_ = m * 16 + li;
#pragma unroll
      for (int n2 = 0; n2 < 8; ++n2) {
        unsigned lo = cvt_pk_bf16(oa[m][n2][0] * inv, oa[m][n2][1] * inv);
        unsigned hi = cvt_pk_bf16(oa[m][n2][2] * inv, oa[m][n2][3] * inv);
        const int byteo = (q_ * 256 + n2 * 32 + lg * 8) ^ ((q_ & 7) << 4);
        uint2 pr2; pr2.x = lo; pr2.y = hi;
        *(uint2*)(Ol + byteo) = pr2;
      }
    }
    asm volatile("s_waitcnt lgkmcnt(0)" ::: "memory");
#pragma unroll
    for (int rr = 0; rr < 4; ++rr) {
      const int r = rr * 8 + (lane >> 3);
      const size_t grow = (size_t)(b * 2048 + qt * 128 + wave * 32 + r) * 2048 + h * 128;
#pragma unroll
      for (int s2 = 0; s2 < 2; ++s2) {
        const int byteo = (r * 256 + (lane & 7) * 32 + s2 * 16) ^ ((r & 7) << 4);
        const u16x8 val = *(const u16x8*)(Ol + byteo);
        *(u16x8*)&attn_out[grow + (lane & 7) * 16 + s2 * 8] = val;
      }
    }
  }
#undef STAGE_KV
}

// ---------------- launch ----------------
extern "C" void kernel_launch(void* const* d_in, const int* in_sizes, int n_in,
                              void* d_out, int out_size, void* d_ws, size_t ws_size,
                              hipStream_t stream) {
  const float* x    = (const float*)d_in[0];   // [2,2048,2048]
  const int*   kpm  = (const int*)d_in[1];     // [2,2048]
  const float* wqkv = (const float*)d_in[2];   // [6144,2048]
  const float* bqkv = (const float*)d_in[3];   // [6144]
  const float* wout = (const float*)d_in[4];   // [2048,2048]
  const float* bout = (const float*)d_in[5];   // [2048]
  float* out = (float*)d_out;

  char* ws = (char*)d_ws;
  u16* xbf   = (u16*)(ws);                    // 16 MiB: x bf16 [4096,2048]
  u16* wqbf  = (u16*)(ws + (16u << 20));      // 24 MiB: Wqkv bf16 [6144,2048]
  u16* wobf  = (u16*)(ws + (40u << 20));      //  8 MiB: out_w bf16 [2048,2048]
  u16* qkvb  = (u16*)(ws + (48u << 20));      // 48 MiB: qkv bf16 [4096,6144] (V third unused)
  u16* vtb   = (u16*)(ws + (96u << 20));      // 16 MiB: V^T bf16 [32,128,2048]
  u16* attnb = (u16*)(ws + (112u << 20));     // 16 MiB: attn bf16 [4096,2048]

  f2bf3_kernel<<<2048, 256, 0, stream>>>(x,    xbf,  4096 * 2048 / 4,
                                         wqkv, wqbf, 6144 * 2048 / 4,
                                         wout, wobf, 2048 * 2048 / 4);

  gemm_qkv<<<768, 512, 0, stream>>>(xbf, wqbf, bqkv, qkvb, vtb, 4096, 6144, 2048);
  attn_fused<<<dim3(16, 32), 256, 0, stream>>>(qkvb, vtb, kpm, attnb);
  gemm_s<0><<<512, 256, 0, stream>>>(attnb, wobf, bout, out, 4096, 2048, 2048);
}